// Round 16
// baseline (204.307 us; speedup 1.0000x reference)
//
#include <hip/hip_runtime.h>
#include <hip/hip_bf16.h>
#include <cmath>

// Problem constants (fixed by reference)
#define NB   4      // batch
#define LQ   2048   // query len
#define SK   2048   // source len
#define DD   256    // in depth
#define HD   256    // hidden
#define FC   8      // heads
#define CH   32     // channels per head (HD/FC)
#define MHEAD 32    // NB*FC

// hh-filter margin: |f32dot - bf16dot| <= 2*2^-9 per side (unit rows) + slack
#define MARGIN 0.0085f
#define CAP    16   // candidate slots per row (avg ~1.2 with global threshold)

// LDS K staging: 128-row groups, rows padded to 80B (40 shorts)
#define KROW 40

typedef float f32x16 __attribute__((ext_vector_type(16)));
typedef float f32x2  __attribute__((ext_vector_type(2)));
typedef short bf16x8 __attribute__((ext_vector_type(8)));
typedef unsigned short ushort8v __attribute__((ext_vector_type(8)));

__device__ inline unsigned short f32_to_bf16_bits(float v) {
    __hip_bfloat16 b = __float2bfloat16(v);   // round-to-nearest
    return __builtin_bit_cast(unsigned short, b);
}
__device__ inline unsigned int ord_encode(float v) {
    unsigned int u = __float_as_uint(v);
    return (u & 0x80000000u) ? ~u : (u | 0x80000000u);
}
__device__ inline float ord_decode(unsigned int e) {
    unsigned int u = (e & 0x80000000u) ? (e & 0x7fffffffu) : ~e;
    return __uint_as_float(u);
}

#define MFMA32(a, b, c) __builtin_amdgcn_mfma_f32_32x32x16_bf16(a, b, c, 0, 0, 0)

// ------------------------------------------------------------------
// Exact-f32 projection GEMM + FUSED L2-norm/bf16-split epilogue
// (R14/R15-proven). q (W0, nt 0-3) + k-point (W1 point cols, nt 4-7).
// ------------------------------------------------------------------
__global__ __launch_bounds__(256, 7)
void proj_gemm_kernel(const float* __restrict__ x0, const float* __restrict__ x1,
                      const float* __restrict__ W0, const float* __restrict__ b0f,
                      const float* __restrict__ W1, const float* __restrict__ b1f,
                      const float* __restrict__ alpha,
                      float* __restrict__ xq, float* __restrict__ xk,
                      unsigned short* __restrict__ qhi, unsigned short* __restrict__ khi)
{
    __shared__ float SH[4224];   // As[2][16][68] + Bs[2][16][64]
    #define AS(bf,k,m) SH[(bf)*1088 + (k)*68 + (m)]
    #define BS(bf,k,n) SH[2176 + (bf)*1024 + (k)*64 + (n)]
    const int nt  = blockIdx.x;        // 0..7 (wave-uniform branch)
    const bool is0 = (nt < 4);
    const float* A    = is0 ? x0 : x1;
    const float* B    = is0 ? W0 : W1;
    const float* bias = is0 ? b0f : b1f;
    float* dst              = is0 ? xq : xk;
    unsigned short* dhi     = is0 ? qhi : khi;
    const int NB_ = is0 ? HD : 2 * HD;   // B row stride
    const int hw  = is0 ? 32 : 64;       // per-head column stride in B/bias
    const int bm  = blockIdx.y * 64;
    const int K   = DD;

    const int tx = threadIdx.x & 15;
    const int ty = threadIdx.x >> 4;
    f32x2 acc2[4][2] = {};

    const int arow = threadIdx.x >> 2;           // 0..63
    const int akq  = (threadIdx.x & 3) << 2;     // 0,4,8,12
    const int bkr  = threadIdx.x >> 4;           // 0..15
    const int bnq  = (threadIdx.x & 15) << 2;    // 0..60
    const int fl   = (nt & 3) * 2 + (bnq >> 5);  // head of loaded cols
    const int bcol = fl * hw + (bnq & 31);

    {
        const float4 a4 = *(const float4*)&A[(size_t)(bm + arow) * K + akq];
        const float4 b4 = *(const float4*)&B[(size_t)bkr * NB_ + bcol];
        AS(0, akq + 0, arow) = a4.x;
        AS(0, akq + 1, arow) = a4.y;
        AS(0, akq + 2, arow) = a4.z;
        AS(0, akq + 3, arow) = a4.w;
        *(float4*)&BS(0, bkr, bnq) = b4;
    }
    __syncthreads();

    const int nchunk = K >> 4;   // 16
    float4 pa, pb;
    for (int c = 0; c < nchunk; ++c) {
        const int cur = c & 1;
        if (c + 1 < nchunk) {
            const int k0 = (c + 1) << 4;
            pa = *(const float4*)&A[(size_t)(bm + arow) * K + k0 + akq];
            pb = *(const float4*)&B[(size_t)(k0 + bkr) * NB_ + bcol];
        }
        #pragma unroll
        for (int kk = 0; kk < 16; ++kk) {
            const float4 a4 = *(const float4*)&AS(cur, kk, ty << 2);
            const float4 bv = *(const float4*)&BS(cur, kk, tx << 2);
            const f32x2 b01 = {bv.x, bv.y};
            const f32x2 b23 = {bv.z, bv.w};
            const float av[4] = {a4.x, a4.y, a4.z, a4.w};
            #pragma unroll
            for (int i = 0; i < 4; ++i) {
                const f32x2 aa = {av[i], av[i]};
                acc2[i][0] = __builtin_elementwise_fma(aa, b01, acc2[i][0]);
                acc2[i][1] = __builtin_elementwise_fma(aa, b23, acc2[i][1]);
            }
        }
        if (c + 1 < nchunk) {
            const int nxt = cur ^ 1;
            AS(nxt, akq + 0, arow) = pa.x;
            AS(nxt, akq + 1, arow) = pa.y;
            AS(nxt, akq + 2, arow) = pa.z;
            AS(nxt, akq + 3, arow) = pa.w;
            *(float4*)&BS(nxt, bkr, bnq) = pb;
        }
        __syncthreads();
    }

    // ---- fused epilogue: stage tile in dead LDS, normalize, split ----
    #pragma unroll
    for (int i = 0; i < 4; ++i) {
        const int row = (ty << 2) + i;
        #pragma unroll
        for (int j = 0; j < 4; ++j) {
            const int cl = (tx << 2) + j;
            const int f  = (nt & 3) * 2 + (cl >> 5);
            SH[row * 66 + cl] = acc2[i][j >> 1][j & 1] + bias[f * hw + (cl & 31)];
        }
    }
    __syncthreads();
    if (threadIdx.x < 128) {
        const int row  = threadIdx.x >> 1;      // 0..63 local m-row
        const int half = threadIdx.x & 1;       // head half within the 64 cols
        const float* src = SH + row * 66 + half * 32;
        float x[32];
        float ss = 0.f;
        #pragma unroll
        for (int c = 0; c < 32; ++c) {          // R2's exact sequential chain
            x[c] = src[c];
            ss = fmaf(x[c], x[c], ss);
        }
        float sgn = 1.f;
        if (is0 && alpha[0] < 0.f) sgn = -1.f;
        const float inv = sgn / fmaxf(sqrtf(ss), 1e-12f);
        const int grow = bm + row;
        const int n = grow >> 11, l = grow & 2047;
        const int f = (nt & 3) * 2 + half;
        const size_t off = ((((size_t)n * FC + f) * LQ) + l) * CH;
        float* df = dst + off;
        unsigned short* dh = dhi + off;
        #pragma unroll
        for (int c4 = 0; c4 < 8; ++c4) {
            float4 w;
            w.x = x[c4 * 4 + 0] * inv;
            w.y = x[c4 * 4 + 1] * inv;
            w.z = x[c4 * 4 + 2] * inv;
            w.w = x[c4 * 4 + 3] * inv;
            *(float4*)(df + c4 * 4) = w;
        }
        #pragma unroll
        for (int c8 = 0; c8 < 4; ++c8) {
            ushort8v o;
            #pragma unroll
            for (int j = 0; j < 8; ++j)
                o[j] = f32_to_bf16_bits(x[c8 * 8 + j] * inv);
            *(ushort8v*)(dh + c8 * 8) = o;
        }
    }
    #undef AS
    #undef BS
}

// ------------------------------------------------------------------
// Prep: x1 -> bf16 rows; Wm and W1-value cols -> bf16 B-frag swizzle;
// zero-init maxhh_u and cnt. Grid: 2048 blocks.
// ------------------------------------------------------------------
__global__ __launch_bounds__(256)
void prep_kernel(const float* __restrict__ x1, const float* __restrict__ Wm,
                 const float* __restrict__ W1,
                 unsigned short* __restrict__ x1b,
                 unsigned short* __restrict__ wm_s,
                 unsigned short* __restrict__ wv_s,
                 unsigned int* __restrict__ maxhh_u, int* __restrict__ cnt)
{
    const int i = blockIdx.x * 256 + threadIdx.x;
    if (i < 262144) {
        const float4 a = *(const float4*)(x1 + (size_t)i * 8);
        const float4 b = *(const float4*)(x1 + (size_t)i * 8 + 4);
        ushort8v o;
        o[0] = f32_to_bf16_bits(a.x); o[1] = f32_to_bf16_bits(a.y);
        o[2] = f32_to_bf16_bits(a.z); o[3] = f32_to_bf16_bits(a.w);
        o[4] = f32_to_bf16_bits(b.x); o[5] = f32_to_bf16_bits(b.y);
        o[6] = f32_to_bf16_bits(b.z); o[7] = f32_to_bf16_bits(b.w);
        *(ushort8v*)(x1b + (size_t)i * 8) = o;
    } else if (i < 327680) {
        const int j = i - 262144;
        const int k = j >> 8, n = j & 255;
        wm_s[(k >> 4) * 4096 + n * 16 + (k & 15)] = f32_to_bf16_bits(Wm[k * 256 + n]);
    } else if (i < 393216) {
        const int j = i - 327680;
        const int k = j >> 8, v = j & 255;
        const int w = (v >> 5) * 64 + 32 + (v & 31);
        wv_s[(k >> 4) * 4096 + v * 16 + (k & 15)] = f32_to_bf16_bits(W1[k * 512 + w]);
    } else if (i < 458752) {
        maxhh_u[i - 393216] = 0u;   // 0 < any ord-encoded float
    } else {
        cnt[i - 458752] = 0;
    }
}

// ------------------------------------------------------------------
// Value projection via bf16 MFMA: x1v = x1 @ W1value + b1value.
// ------------------------------------------------------------------
__global__ __launch_bounds__(256)
void val_gemm_kernel(const unsigned short* __restrict__ x1b,
                     const unsigned short* __restrict__ wv_s,
                     const float* __restrict__ b1f, float* __restrict__ xv)
{
    const int wave = threadIdx.x >> 6;
    const int lane = threadIdx.x & 63;
    const int idx  = blockIdx.x * 4 + wave;
    const int mt   = idx >> 3;
    const int nt   = idx & 7;
    const int col  = lane & 31;
    const int g8   = (lane >> 5) * 8;

    const unsigned short* aptr = x1b + (size_t)(mt * 32 + col) * 256 + g8;
    const unsigned short* bptr = wv_s + nt * 32 * 16 + col * 16 + g8;

    f32x16 acc = {0.f, 0.f, 0.f, 0.f, 0.f, 0.f, 0.f, 0.f,
                  0.f, 0.f, 0.f, 0.f, 0.f, 0.f, 0.f, 0.f};
    #pragma unroll 4
    for (int kc = 0; kc < 16; ++kc) {
        const bf16x8 a = *(const bf16x8*)(aptr + kc * 16);
        const bf16x8 bfr = *(const bf16x8*)(bptr + (size_t)kc * 4096);
        acc = MFMA32(a, bfr, acc);
    }

    const int v = nt * 32 + col;
    const int f = v >> 5, c = v & 31;
    const float bias = b1f[f * 64 + 32 + c];
    #pragma unroll
    for (int r = 0; r < 16; ++r) {
        const int g = mt * 32 + (r & 3) + 8 * (r >> 2) + 4 * (lane >> 5);
        const int n = g >> 11, s = g & 2047;
        xv[((((size_t)n * FC + f) * SK) + s) * CH + c] = acc[r] + bias;
    }
}

// ------------------------------------------------------------------
// Pass A1 v6: 256 q-rows per block (2 q-sets/wave) vs 512-row k-chunk.
// Each staged LDS tile feeds 8 MFMAs (was 4): LDS reads/MFMA halve,
// 2 independent acc chains/wave, K global staging traffic halves.
// This is R10's 2-qset idea done in LDS (R10 spilled in registers).
// MFMA inputs per (row, s) identical to R15 -> same maxes bit-for-bit.
// Grid: 32 heads * 8 qp * 4 sc = 1024 blocks, 256 thr, 4 waves.
// ------------------------------------------------------------------
__global__ __launch_bounds__(256, 4)
void maxpass_kernel(const unsigned short* __restrict__ qhi,
                    const unsigned short* __restrict__ khi,
                    unsigned int* __restrict__ maxhh_u)
{
    __shared__ unsigned short kbuf[2][128 * KROW];   // 2 x 10240B
    const int b    = blockIdx.x;
    const int sc   = b & 3;
    const int qp   = (b >> 2) & 7;
    const int h    = b >> 5;
    const int wave = threadIdx.x >> 6;
    const int lane = threadIdx.x & 63;
    const int t    = threadIdx.x;
    const int qb0  = qp * 256 + wave * 32;   // q-set 0 rows
    const int col  = lane & 31;
    const int g8   = (lane >> 5) * 8;

    const size_t qoff0 = ((size_t)h * LQ + qb0 + col) * CH + g8;
    const size_t qoff1 = qoff0 + (size_t)128 * CH;   // q-set 1 = +128 rows
    const bf16x8 a00 = *(const bf16x8*)(qhi + qoff0);
    const bf16x8 a01 = *(const bf16x8*)(qhi + qoff0 + 16);
    const bf16x8 a10 = *(const bf16x8*)(qhi + qoff1);
    const bf16x8 a11 = *(const bf16x8*)(qhi + qoff1 + 16);

    const unsigned short* kh = khi + ((size_t)h * SK + sc * 512) * CH;

    // staging: thread t owns row t>>1, 16-short half t&1 of each group
    const int srow  = t >> 1;
    const int shalf = (t & 1) * 16;
    const unsigned short* sp = kh + (size_t)srow * CH + shalf;

    float m0[16], m1[16];
    #pragma unroll
    for (int r = 0; r < 16; ++r) { m0[r] = -INFINITY; m1[r] = -INFINITY; }

    bf16x8 s0 = *(const bf16x8*)(sp);
    bf16x8 s1 = *(const bf16x8*)(sp + 8);
    *(bf16x8*)(&kbuf[0][srow * KROW + shalf])     = s0;
    *(bf16x8*)(&kbuf[0][srow * KROW + shalf + 8]) = s1;
    __syncthreads();

    for (int g = 0; g < 4; ++g) {
        if (g < 3) {
            const unsigned short* spn = sp + (size_t)(g + 1) * 128 * CH;
            s0 = *(const bf16x8*)(spn);
            s1 = *(const bf16x8*)(spn + 8);
        }
        const unsigned short* kbp = &kbuf[g & 1][0];
        #pragma unroll
        for (int tt = 0; tt < 4; ++tt) {
            const int rl = tt * 32 + col;
            const bf16x8 ka  = *(const bf16x8*)(kbp + rl * KROW + g8);
            const bf16x8 kbv = *(const bf16x8*)(kbp + rl * KROW + 16 + g8);
            f32x16 c0 = {0.f, 0.f, 0.f, 0.f, 0.f, 0.f, 0.f, 0.f,
                         0.f, 0.f, 0.f, 0.f, 0.f, 0.f, 0.f, 0.f};
            f32x16 c1 = c0;
            c0 = MFMA32(a00, ka, c0);
            c1 = MFMA32(a10, ka, c1);
            c0 = MFMA32(a01, kbv, c0);
            c1 = MFMA32(a11, kbv, c1);
            #pragma unroll
            for (int r = 0; r < 16; ++r) {
                m0[r] = fmaxf(m0[r], c0[r]);
                m1[r] = fmaxf(m1[r], c1[r]);
            }
        }
        if (g < 3) {
            unsigned short* swn = &kbuf[(g + 1) & 1][srow * KROW + shalf];
            *(bf16x8*)(swn)     = s0;
            *(bf16x8*)(swn + 8) = s1;
            __syncthreads();
        }
    }

    #pragma unroll
    for (int r = 0; r < 16; ++r) {
        float v0 = m0[r], v1 = m1[r];
        #pragma unroll
        for (int m = 16; m >= 1; m >>= 1) {
            v0 = fmaxf(v0, __shfl_xor(v0, m, 64));
            v1 = fmaxf(v1, __shfl_xor(v1, m, 64));
        }
        m0[r] = v0; m1[r] = v1;
    }
    if (col == 0) {
        const int rbase = h * LQ + qb0 + 4 * (lane >> 5);
        #pragma unroll
        for (int r = 0; r < 16; ++r) {
            const int crow = (r & 3) + 8 * (r >> 2);
            atomicMax(&maxhh_u[rbase + crow], ord_encode(m0[r]));
            atomicMax(&maxhh_u[rbase + 128 + crow], ord_encode(m1[r]));
        }
    }
}

// ------------------------------------------------------------------
// Pass A2 v6: same 2-q-set LDS-staged scan; append s with
// hh >= globalmax - MARGIN. Candidate SET identical to R15 (order
// differs; refine is set-based with s-index tie-break).
// ------------------------------------------------------------------
__global__ __launch_bounds__(256, 4)
void candpass_kernel(const unsigned short* __restrict__ qhi,
                     const unsigned short* __restrict__ khi,
                     const unsigned int* __restrict__ maxhh_u,
                     int* __restrict__ cnt, int* __restrict__ cand)
{
    __shared__ unsigned short kbuf[2][128 * KROW];
    const int b    = blockIdx.x;
    const int sc   = b & 3;
    const int qp   = (b >> 2) & 7;
    const int h    = b >> 5;
    const int wave = threadIdx.x >> 6;
    const int lane = threadIdx.x & 63;
    const int t    = threadIdx.x;
    const int qb0  = qp * 256 + wave * 32;
    const int col  = lane & 31;
    const int g8   = (lane >> 5) * 8;

    const size_t qoff0 = ((size_t)h * LQ + qb0 + col) * CH + g8;
    const size_t qoff1 = qoff0 + (size_t)128 * CH;
    const bf16x8 a00 = *(const bf16x8*)(qhi + qoff0);
    const bf16x8 a01 = *(const bf16x8*)(qhi + qoff0 + 16);
    const bf16x8 a10 = *(const bf16x8*)(qhi + qoff1);
    const bf16x8 a11 = *(const bf16x8*)(qhi + qoff1 + 16);

    const int rbase = h * LQ + qb0 + 4 * (lane >> 5);
    float thr0[16], thr1[16];
    #pragma unroll
    for (int r = 0; r < 16; ++r) {
        const int crow = (r & 3) + 8 * (r >> 2);
        thr0[r] = ord_decode(maxhh_u[rbase + crow]) - MARGIN;
        thr1[r] = ord_decode(maxhh_u[rbase + 128 + crow]) - MARGIN;
    }

    const unsigned short* kh = khi + ((size_t)h * SK + sc * 512) * CH;
    const int sbase = sc * 512;

    const int srow  = t >> 1;
    const int shalf = (t & 1) * 16;
    const unsigned short* sp = kh + (size_t)srow * CH + shalf;

    bf16x8 s0 = *(const bf16x8*)(sp);
    bf16x8 s1 = *(const bf16x8*)(sp + 8);
    *(bf16x8*)(&kbuf[0][srow * KROW + shalf])     = s0;
    *(bf16x8*)(&kbuf[0][srow * KROW + shalf + 8]) = s1;
    __syncthreads();

    for (int g = 0; g < 4; ++g) {
        if (g < 3) {
            const unsigned short* spn = sp + (size_t)(g + 1) * 128 * CH;
            s0 = *(const bf16x8*)(spn);
            s1 = *(const bf16x8*)(spn + 8);
        }
        const unsigned short* kbp = &kbuf[g & 1][0];
        #pragma unroll
        for (int tt = 0; tt < 4; ++tt) {
            const int rl = tt * 32 + col;
            const bf16x8 ka  = *(const bf16x8*)(kbp + rl * KROW + g8);
            const bf16x8 kbv = *(const bf16x8*)(kbp + rl * KROW + 16 + g8);
            const int s = sbase + g * 128 + tt * 32 + col;

            f32x16 c0 = {0.f, 0.f, 0.f, 0.f, 0.f, 0.f, 0.f, 0.f,
                         0.f, 0.f, 0.f, 0.f, 0.f, 0.f, 0.f, 0.f};
            f32x16 c1 = c0;
            c0 = MFMA32(a00, ka, c0);
            c1 = MFMA32(a10, ka, c1);
            c0 = MFMA32(a01, kbv, c0);
            c1 = MFMA32(a11, kbv, c1);

            unsigned int hit0 = 0u, hit1 = 0u;
            #pragma unroll
            for (int r = 0; r < 16; ++r) {
                hit0 = (c0[r] >= thr0[r]) ? (hit0 | (1u << r)) : hit0;
                hit1 = (c1[r] >= thr1[r]) ? (hit1 | (1u << r)) : hit1;
            }
            if (hit0) {
                #pragma unroll
                for (int r = 0; r < 16; ++r) {
                    if (hit0 & (1u << r)) {
                        const int row = rbase + (r & 3) + 8 * (r >> 2);
                        const int slot = atomicAdd(&cnt[row], 1);
                        if (slot < CAP) cand[(size_t)row * CAP + slot] = s;
                    }
                }
            }
            if (hit1) {
                #pragma unroll
                for (int r = 0; r < 16; ++r) {
                    if (hit1 & (1u << r)) {
                        const int row = rbase + 128 + (r & 3) + 8 * (r >> 2);
                        const int slot = atomicAdd(&cnt[row], 1);
                        if (slot < CAP) cand[(size_t)row * CAP + slot] = s;
                    }
                }
            }
        }
        if (g < 3) {
            unsigned short* swn = &kbuf[(g + 1) & 1][srow * KROW + shalf];
            *(bf16x8*)(swn)     = s0;
            *(bf16x8*)(swn + 8) = s1;
            __syncthreads();
        }
    }
}

// ------------------------------------------------------------------
// Pass B: exact f32 refine (chain bit-identical to R2) + sigmoid +
// gather + scale; writes new_x0 as bf16 for the MFMA output GEMM.
// ------------------------------------------------------------------
__global__ __launch_bounds__(256)
void refine_gather_kernel(const float* __restrict__ qn,
                          const float* __restrict__ kn,
                          const int* __restrict__ cnt, const int* __restrict__ cand,
                          const float* __restrict__ xv,
                          const float* __restrict__ alpha, const float* __restrict__ beta,
                          unsigned short* __restrict__ nxb)  // (4,2048,256) bf16
{
    const int r = blockIdx.x * blockDim.x + threadIdx.x;  // h*2048 + l
    const int h = r >> 11, l = r & 2047;

    float qr[CH];
    #pragma unroll
    for (int i = 0; i < 8; ++i) {
        const float4 v = *(const float4*)(qn + (size_t)r * CH + i * 4);
        qr[i * 4 + 0] = v.x; qr[i * 4 + 1] = v.y;
        qr[i * 4 + 2] = v.z; qr[i * 4 + 3] = v.w;
    }

    int m = cnt[r];
    if (m > CAP) m = CAP;
    float best = -INFINITY;
    int   bidx = 0x7fffffff;
    for (int j = 0; j < m; ++j) {
        const int s = cand[(size_t)r * CAP + j];
        const float4* k4 = (const float4*)(kn + ((size_t)h * SK + s) * CH);
        float p = 0.f;
        #pragma unroll
        for (int c = 0; c < 8; ++c) {
            const float4 kv = k4[c];
            p = fmaf(qr[c * 4 + 0], kv.x, p);
            p = fmaf(qr[c * 4 + 1], kv.y, p);
            p = fmaf(qr[c * 4 + 2], kv.z, p);
            p = fmaf(qr[c * 4 + 3], kv.w, p);
        }
        if (p > best || (p == best && s < bidx)) { best = p; bidx = s; }
    }
    if (bidx == 0x7fffffff) bidx = 0;   // unreachable guard

    const float a = alpha[0], be = beta[0];
    float tv;
    int idx = bidx;
    if (a == 0.f) { idx = 0; tv = be; }
    else          { tv = fmaf(fabsf(a), best, be); }
    float val;
    if (tv >= 0.f) val = 1.f / (1.f + expf(-tv));
    else           { const float e = expf(tv); val = e / (1.f + e); }

    const float4* vr = (const float4*)(xv + ((size_t)h * SK + idx) * CH);
    const int n = h >> 3, f = h & 7;
    unsigned short* out = nxb + (((size_t)n * LQ + l) * (FC * CH)) + f * CH;
    #pragma unroll
    for (int i = 0; i < 8; ++i) {
        const float4 w = vr[i];
        ushort8v o;
        o[0] = f32_to_bf16_bits(w.x * val);
        o[1] = f32_to_bf16_bits(w.y * val);
        o[2] = f32_to_bf16_bits(w.z * val);
        o[3] = f32_to_bf16_bits(w.w * val);
        *(unsigned long long*)(out + i * 4) = __builtin_bit_cast(unsigned long long,
            *(const ulong1*)&o);
    }
}

// ------------------------------------------------------------------
// K6: out = nx(bf16) @ Wm(bf16 swizzled) + bm, f32 out. MFMA 32x32.
// ------------------------------------------------------------------
__global__ __launch_bounds__(256)
void gemm_out_mfma_kernel(const unsigned short* __restrict__ nxb,
                          const unsigned short* __restrict__ wm_s,
                          const float* __restrict__ bm, float* __restrict__ out)
{
    const int wave = threadIdx.x >> 6;
    const int lane = threadIdx.x & 63;
    const int idx  = blockIdx.x * 4 + wave;
    const int mt   = idx >> 3;
    const int nt   = idx & 7;
    const int col  = lane & 31;
    const int g8   = (lane >> 5) * 8;

    const unsigned short* aptr = nxb + (size_t)(mt * 32 + col) * 256 + g8;
    const unsigned short* bptr = wm_s + nt * 32 * 16 + col * 16 + g8;

    f32x16 acc = {0.f, 0.f, 0.f, 0.f, 0.f, 0.f, 0.f, 0.f,
                  0.f, 0.f, 0.f, 0.f, 0.f, 0.f, 0.f, 0.f};
    #pragma unroll 4
    for (int kc = 0; kc < 16; ++kc) {
        const bf16x8 a = *(const bf16x8*)(aptr + kc * 16);
        const bf16x8 bfr = *(const bf16x8*)(bptr + (size_t)kc * 4096);
        acc = MFMA32(a, bfr, acc);
    }

    const int n0 = nt * 32;
    const float bias = bm[n0 + col];
    #pragma unroll
    for (int r = 0; r < 16; ++r) {
        const int row = mt * 32 + (r & 3) + 8 * (r >> 2) + 4 * (lane >> 5);
        out[(size_t)row * 256 + n0 + col] = acc[r] + bias;
    }
}

// ------------------------------------------------------------------
extern "C" void kernel_launch(void* const* d_in, const int* in_sizes, int n_in,
                              void* d_out, int out_size, void* d_ws, size_t ws_size,
                              hipStream_t stream)
{
    const float* x0 = (const float*)d_in[0];
    const float* x1 = (const float*)d_in[1];
    const float* W0 = (const float*)d_in[2];
    const float* b0 = (const float*)d_in[3];
    const float* W1 = (const float*)d_in[4];
    const float* b1 = (const float*)d_in[5];
    const float* Wm = (const float*)d_in[6];
    const float* bm = (const float*)d_in[7];
    const float* alpha = (const float*)d_in[8];
    const float* beta  = (const float*)d_in[9];
    float* out = (float*)d_out;

    char* ws = (char*)d_ws;
    const size_t MB = 1024ull * 1024ull;
    float* x0q = (float*)(ws + 0);          // (32,2048,32) f32 normalized
    float* x1k = (float*)(ws + 8 * MB);     // (32,2048,32) f32 normalized
    float* x1v = (float*)(ws + 16 * MB);    // (32,2048,32) f32 values
    unsigned short* qhi = (unsigned short*)(ws + 24 * MB);  // 4MB (dead after scan)
    unsigned short* khi = (unsigned short*)(ws + 28 * MB);  // 4MB
    unsigned short* x1b = (unsigned short*)(ws + 32 * MB);  // 4MB (dead after valgemm)
    int* cand = (int*)(ws + 32 * MB);       // 4MB CAP16 (reuses x1b; valgemm reads
                                            // x1b before candpass writes cand)
    unsigned int* maxhh_u = (unsigned int*)(ws + 36 * MB);          // 256KB
    int* cnt  = (int*)(ws + 36 * MB + 256 * 1024);                  // 256KB
    unsigned short* wm_s = (unsigned short*)(ws + 36 * MB + 512 * 1024); // 128KB
    unsigned short* wv_s = (unsigned short*)(ws + 36 * MB + 640 * 1024); // 128KB
    unsigned short* nxb  = (unsigned short*)(ws + 24 * MB); // reuse qhi region

    const int Mrows = NB * LQ;   // 8192

    // 1) exact-f32 projections + fused norm/bf16-split (argmax path)
    proj_gemm_kernel<<<dim3(8, Mrows / 64), 256, 0, stream>>>(
        x0, x1, W0, b0, W1, b1, alpha, x0q, x1k, qhi, khi);
    // 2) preps: x1->bf16, Wm & W1-value swizzles, zero maxhh/cnt
    prep_kernel<<<2048, 256, 0, stream>>>(x1, Wm, W1, x1b, wm_s, wv_s, maxhh_u, cnt);
    // 3) value projection via bf16 MFMA
    val_gemm_kernel<<<512, 256, 0, stream>>>(x1b, wv_s, b1, x1v);
    // 4) global hh max (2 q-sets/wave, LDS-staged K)
    maxpass_kernel<<<1024, 256, 0, stream>>>(qhi, khi, maxhh_u);
    // 5) candidate collection vs global threshold (2 q-sets/wave)
    candpass_kernel<<<1024, 256, 0, stream>>>(qhi, khi, maxhh_u, cnt, cand);
    // 6) exact refine + sigmoid + gather + scale -> bf16 nx
    refine_gather_kernel<<<(MHEAD * LQ) / 256, 256, 0, stream>>>(
        x0q, x1k, cnt, cand, x1v, alpha, beta, nxb);
    // 7) out = nx @ Wm + bm via bf16 MFMA
    gemm_out_mfma_kernel<<<512, 256, 0, stream>>>(nxb, wm_s, bm, out);
}

// Round 17
// 125.893 us; speedup vs baseline: 1.6229x; 1.6229x over previous
//
#include <hip/hip_runtime.h>
#include <hip/hip_bf16.h>
#include <cmath>

// Problem constants (fixed by reference)
#define NB   4      // batch
#define LQ   2048   // query len
#define SK   2048   // source len
#define DD   256    // in depth
#define HD   256    // hidden
#define FC   8      // heads
#define CH   32     // channels per head (HD/FC)
#define MHEAD 32    // NB*FC

// hh-filter margin: |f32dot - bf16dot| <= 2*2^-9 per side (unit rows) + slack
#define MARGIN 0.0085f
#define CAP    16   // candidate slots per row (avg ~1.2 with global threshold)

// LDS K staging: 128-row groups, rows padded to 80B (40 shorts)
#define KROW 40

typedef float f32x16 __attribute__((ext_vector_type(16)));
typedef float f32x2  __attribute__((ext_vector_type(2)));
typedef short bf16x8 __attribute__((ext_vector_type(8)));
typedef unsigned short ushort8v __attribute__((ext_vector_type(8)));

__device__ inline unsigned short f32_to_bf16_bits(float v) {
    __hip_bfloat16 b = __float2bfloat16(v);   // round-to-nearest
    return __builtin_bit_cast(unsigned short, b);
}
__device__ inline unsigned int ord_encode(float v) {
    unsigned int u = __float_as_uint(v);
    return (u & 0x80000000u) ? ~u : (u | 0x80000000u);
}
__device__ inline float ord_decode(unsigned int e) {
    unsigned int u = (e & 0x80000000u) ? (e & 0x7fffffffu) : ~e;
    return __uint_as_float(u);
}

#define MFMA32(a, b, c) __builtin_amdgcn_mfma_f32_32x32x16_bf16(a, b, c, 0, 0, 0)

// ------------------------------------------------------------------
// Exact-f32 projection GEMM + FUSED L2-norm/bf16-split epilogue
// (R14/R15-proven). q (W0, nt 0-3) + k-point (W1 point cols, nt 4-7).
// ------------------------------------------------------------------
__global__ __launch_bounds__(256, 7)
void proj_gemm_kernel(const float* __restrict__ x0, const float* __restrict__ x1,
                      const float* __restrict__ W0, const float* __restrict__ b0f,
                      const float* __restrict__ W1, const float* __restrict__ b1f,
                      const float* __restrict__ alpha,
                      float* __restrict__ xq, float* __restrict__ xk,
                      unsigned short* __restrict__ qhi, unsigned short* __restrict__ khi)
{
    __shared__ float SH[4224];   // As[2][16][68] + Bs[2][16][64]
    #define AS(bf,k,m) SH[(bf)*1088 + (k)*68 + (m)]
    #define BS(bf,k,n) SH[2176 + (bf)*1024 + (k)*64 + (n)]
    const int nt  = blockIdx.x;        // 0..7 (wave-uniform branch)
    const bool is0 = (nt < 4);
    const float* A    = is0 ? x0 : x1;
    const float* B    = is0 ? W0 : W1;
    const float* bias = is0 ? b0f : b1f;
    float* dst              = is0 ? xq : xk;
    unsigned short* dhi     = is0 ? qhi : khi;
    const int NB_ = is0 ? HD : 2 * HD;   // B row stride
    const int hw  = is0 ? 32 : 64;       // per-head column stride in B/bias
    const int bm  = blockIdx.y * 64;
    const int K   = DD;

    const int tx = threadIdx.x & 15;
    const int ty = threadIdx.x >> 4;
    f32x2 acc2[4][2] = {};

    const int arow = threadIdx.x >> 2;           // 0..63
    const int akq  = (threadIdx.x & 3) << 2;     // 0,4,8,12
    const int bkr  = threadIdx.x >> 4;           // 0..15
    const int bnq  = (threadIdx.x & 15) << 2;    // 0..60
    const int fl   = (nt & 3) * 2 + (bnq >> 5);  // head of loaded cols
    const int bcol = fl * hw + (bnq & 31);

    {
        const float4 a4 = *(const float4*)&A[(size_t)(bm + arow) * K + akq];
        const float4 b4 = *(const float4*)&B[(size_t)bkr * NB_ + bcol];
        AS(0, akq + 0, arow) = a4.x;
        AS(0, akq + 1, arow) = a4.y;
        AS(0, akq + 2, arow) = a4.z;
        AS(0, akq + 3, arow) = a4.w;
        *(float4*)&BS(0, bkr, bnq) = b4;
    }
    __syncthreads();

    const int nchunk = K >> 4;   // 16
    float4 pa, pb;
    for (int c = 0; c < nchunk; ++c) {
        const int cur = c & 1;
        if (c + 1 < nchunk) {
            const int k0 = (c + 1) << 4;
            pa = *(const float4*)&A[(size_t)(bm + arow) * K + k0 + akq];
            pb = *(const float4*)&B[(size_t)(k0 + bkr) * NB_ + bcol];
        }
        #pragma unroll
        for (int kk = 0; kk < 16; ++kk) {
            const float4 a4 = *(const float4*)&AS(cur, kk, ty << 2);
            const float4 bv = *(const float4*)&BS(cur, kk, tx << 2);
            const f32x2 b01 = {bv.x, bv.y};
            const f32x2 b23 = {bv.z, bv.w};
            const float av[4] = {a4.x, a4.y, a4.z, a4.w};
            #pragma unroll
            for (int i = 0; i < 4; ++i) {
                const f32x2 aa = {av[i], av[i]};
                acc2[i][0] = __builtin_elementwise_fma(aa, b01, acc2[i][0]);
                acc2[i][1] = __builtin_elementwise_fma(aa, b23, acc2[i][1]);
            }
        }
        if (c + 1 < nchunk) {
            const int nxt = cur ^ 1;
            AS(nxt, akq + 0, arow) = pa.x;
            AS(nxt, akq + 1, arow) = pa.y;
            AS(nxt, akq + 2, arow) = pa.z;
            AS(nxt, akq + 3, arow) = pa.w;
            *(float4*)&BS(nxt, bkr, bnq) = pb;
        }
        __syncthreads();
    }

    // ---- fused epilogue: stage tile in dead LDS, normalize, split ----
    #pragma unroll
    for (int i = 0; i < 4; ++i) {
        const int row = (ty << 2) + i;
        #pragma unroll
        for (int j = 0; j < 4; ++j) {
            const int cl = (tx << 2) + j;
            const int f  = (nt & 3) * 2 + (cl >> 5);
            SH[row * 66 + cl] = acc2[i][j >> 1][j & 1] + bias[f * hw + (cl & 31)];
        }
    }
    __syncthreads();
    if (threadIdx.x < 128) {
        const int row  = threadIdx.x >> 1;      // 0..63 local m-row
        const int half = threadIdx.x & 1;       // head half within the 64 cols
        const float* src = SH + row * 66 + half * 32;
        float x[32];
        float ss = 0.f;
        #pragma unroll
        for (int c = 0; c < 32; ++c) {          // R2's exact sequential chain
            x[c] = src[c];
            ss = fmaf(x[c], x[c], ss);
        }
        float sgn = 1.f;
        if (is0 && alpha[0] < 0.f) sgn = -1.f;
        const float inv = sgn / fmaxf(sqrtf(ss), 1e-12f);
        const int grow = bm + row;
        const int n = grow >> 11, l = grow & 2047;
        const int f = (nt & 3) * 2 + half;
        const size_t off = ((((size_t)n * FC + f) * LQ) + l) * CH;
        float* df = dst + off;
        unsigned short* dh = dhi + off;
        #pragma unroll
        for (int c4 = 0; c4 < 8; ++c4) {
            float4 w;
            w.x = x[c4 * 4 + 0] * inv;
            w.y = x[c4 * 4 + 1] * inv;
            w.z = x[c4 * 4 + 2] * inv;
            w.w = x[c4 * 4 + 3] * inv;
            *(float4*)(df + c4 * 4) = w;
        }
        #pragma unroll
        for (int c8 = 0; c8 < 4; ++c8) {
            ushort8v o;
            #pragma unroll
            for (int j = 0; j < 8; ++j)
                o[j] = f32_to_bf16_bits(x[c8 * 8 + j] * inv);
            *(ushort8v*)(dh + c8 * 8) = o;
        }
    }
    #undef AS
    #undef BS
}

// ------------------------------------------------------------------
// Prep: x1 -> bf16 rows; Wm and W1-value cols -> bf16 B-frag swizzle;
// zero-init maxhh_u and cnt. Grid: 2048 blocks.
// ------------------------------------------------------------------
__global__ __launch_bounds__(256)
void prep_kernel(const float* __restrict__ x1, const float* __restrict__ Wm,
                 const float* __restrict__ W1,
                 unsigned short* __restrict__ x1b,
                 unsigned short* __restrict__ wm_s,
                 unsigned short* __restrict__ wv_s,
                 unsigned int* __restrict__ maxhh_u, int* __restrict__ cnt)
{
    const int i = blockIdx.x * 256 + threadIdx.x;
    if (i < 262144) {
        const float4 a = *(const float4*)(x1 + (size_t)i * 8);
        const float4 b = *(const float4*)(x1 + (size_t)i * 8 + 4);
        ushort8v o;
        o[0] = f32_to_bf16_bits(a.x); o[1] = f32_to_bf16_bits(a.y);
        o[2] = f32_to_bf16_bits(a.z); o[3] = f32_to_bf16_bits(a.w);
        o[4] = f32_to_bf16_bits(b.x); o[5] = f32_to_bf16_bits(b.y);
        o[6] = f32_to_bf16_bits(b.z); o[7] = f32_to_bf16_bits(b.w);
        *(ushort8v*)(x1b + (size_t)i * 8) = o;
    } else if (i < 327680) {
        const int j = i - 262144;
        const int k = j >> 8, n = j & 255;
        wm_s[(k >> 4) * 4096 + n * 16 + (k & 15)] = f32_to_bf16_bits(Wm[k * 256 + n]);
    } else if (i < 393216) {
        const int j = i - 327680;
        const int k = j >> 8, v = j & 255;
        const int w = (v >> 5) * 64 + 32 + (v & 31);
        wv_s[(k >> 4) * 4096 + v * 16 + (k & 15)] = f32_to_bf16_bits(W1[k * 512 + w]);
    } else if (i < 458752) {
        maxhh_u[i - 393216] = 0u;   // 0 < any ord-encoded float
    } else {
        cnt[i - 458752] = 0;
    }
}

// ------------------------------------------------------------------
// Value projection via bf16 MFMA: x1v = x1 @ W1value + b1value.
// ------------------------------------------------------------------
__global__ __launch_bounds__(256)
void val_gemm_kernel(const unsigned short* __restrict__ x1b,
                     const unsigned short* __restrict__ wv_s,
                     const float* __restrict__ b1f, float* __restrict__ xv)
{
    const int wave = threadIdx.x >> 6;
    const int lane = threadIdx.x & 63;
    const int idx  = blockIdx.x * 4 + wave;
    const int mt   = idx >> 3;
    const int nt   = idx & 7;
    const int col  = lane & 31;
    const int g8   = (lane >> 5) * 8;

    const unsigned short* aptr = x1b + (size_t)(mt * 32 + col) * 256 + g8;
    const unsigned short* bptr = wv_s + nt * 32 * 16 + col * 16 + g8;

    f32x16 acc = {0.f, 0.f, 0.f, 0.f, 0.f, 0.f, 0.f, 0.f,
                  0.f, 0.f, 0.f, 0.f, 0.f, 0.f, 0.f, 0.f};
    #pragma unroll 4
    for (int kc = 0; kc < 16; ++kc) {
        const bf16x8 a = *(const bf16x8*)(aptr + kc * 16);
        const bf16x8 bfr = *(const bf16x8*)(bptr + (size_t)kc * 4096);
        acc = MFMA32(a, bfr, acc);
    }

    const int v = nt * 32 + col;
    const int f = v >> 5, c = v & 31;
    const float bias = b1f[f * 64 + 32 + c];
    #pragma unroll
    for (int r = 0; r < 16; ++r) {
        const int g = mt * 32 + (r & 3) + 8 * (r >> 2) + 4 * (lane >> 5);
        const int n = g >> 11, s = g & 2047;
        xv[((((size_t)n * FC + f) * SK) + s) * CH + c] = acc[r] + bias;
    }
}

// ------------------------------------------------------------------
// Pass A1 (R13/R15-proven): 256-thread/4-wave blocks, LDS-staged K in
// 128-row double-buffered groups. Grid: 32h * 16qb * 4sc = 2048.
// NOTE: 32 q-rows/wave with 16 f32 max-state is the edge of the
// 64-VGPR class — adding per-wave state spills (R10/R16, 172MB scratch).
// ------------------------------------------------------------------
__global__ __launch_bounds__(256, 4)
void maxpass_kernel(const unsigned short* __restrict__ qhi,
                    const unsigned short* __restrict__ khi,
                    unsigned int* __restrict__ maxhh_u)
{
    __shared__ unsigned short kbuf[2][128 * KROW];   // 2 x 10240B
    const int b    = blockIdx.x;
    const int sc   = b & 3;
    const int qb   = (b >> 2) & 15;
    const int h    = b >> 6;
    const int wave = threadIdx.x >> 6;
    const int lane = threadIdx.x & 63;
    const int t    = threadIdx.x;
    const int qbase = qb * 128 + wave * 32;
    const int col   = lane & 31;
    const int g8    = (lane >> 5) * 8;

    const size_t qoff = ((size_t)h * LQ + qbase + col) * CH + g8;
    const bf16x8 ah0 = *(const bf16x8*)(qhi + qoff);
    const bf16x8 ah1 = *(const bf16x8*)(qhi + qoff + 16);

    const unsigned short* kh = khi + ((size_t)h * SK + sc * 512) * CH;

    // staging: thread t owns row t>>1, 16-short half t&1 of each group
    const int srow  = t >> 1;
    const int shalf = (t & 1) * 16;
    const unsigned short* sp = kh + (size_t)srow * CH + shalf;

    float maxv[16];
    #pragma unroll
    for (int r = 0; r < 16; ++r) maxv[r] = -INFINITY;

    bf16x8 s0 = *(const bf16x8*)(sp);
    bf16x8 s1 = *(const bf16x8*)(sp + 8);
    *(bf16x8*)(&kbuf[0][srow * KROW + shalf])     = s0;
    *(bf16x8*)(&kbuf[0][srow * KROW + shalf + 8]) = s1;
    __syncthreads();

    for (int g = 0; g < 4; ++g) {
        if (g < 3) {
            const unsigned short* spn = sp + (size_t)(g + 1) * 128 * CH;
            s0 = *(const bf16x8*)(spn);
            s1 = *(const bf16x8*)(spn + 8);
        }
        const unsigned short* kbp = &kbuf[g & 1][0];
        #pragma unroll
        for (int tt = 0; tt < 4; ++tt) {
            const int rl = tt * 32 + col;
            const bf16x8 ka  = *(const bf16x8*)(kbp + rl * KROW + g8);
            const bf16x8 kbv = *(const bf16x8*)(kbp + rl * KROW + 16 + g8);
            f32x16 c = {0.f, 0.f, 0.f, 0.f, 0.f, 0.f, 0.f, 0.f,
                        0.f, 0.f, 0.f, 0.f, 0.f, 0.f, 0.f, 0.f};
            c = MFMA32(ah0, ka, c);
            c = MFMA32(ah1, kbv, c);
            #pragma unroll
            for (int r = 0; r < 16; ++r) maxv[r] = fmaxf(maxv[r], c[r]);
        }
        if (g < 3) {
            unsigned short* swn = &kbuf[(g + 1) & 1][srow * KROW + shalf];
            *(bf16x8*)(swn)     = s0;
            *(bf16x8*)(swn + 8) = s1;
            __syncthreads();
        }
    }

    #pragma unroll
    for (int r = 0; r < 16; ++r) {
        float v = maxv[r];
        #pragma unroll
        for (int m = 16; m >= 1; m >>= 1)
            v = fmaxf(v, __shfl_xor(v, m, 64));
        maxv[r] = v;
    }
    if (col == 0) {
        const int rbase = h * LQ + qbase + 4 * (lane >> 5);
        #pragma unroll
        for (int r = 0; r < 16; ++r)
            atomicMax(&maxhh_u[rbase + (r & 3) + 8 * (r >> 2)], ord_encode(maxv[r]));
    }
}

// ------------------------------------------------------------------
// Pass A2 (R13/R15-proven): LDS-staged scan; append s with
// hh >= globalmax - MARGIN. 256-thread/4-wave. Grid: 2048 blocks.
// ------------------------------------------------------------------
__global__ __launch_bounds__(256, 4)
void candpass_kernel(const unsigned short* __restrict__ qhi,
                     const unsigned short* __restrict__ khi,
                     const unsigned int* __restrict__ maxhh_u,
                     int* __restrict__ cnt, int* __restrict__ cand)
{
    __shared__ unsigned short kbuf[2][128 * KROW];
    const int b    = blockIdx.x;
    const int sc   = b & 3;
    const int qb   = (b >> 2) & 15;
    const int h    = b >> 6;
    const int wave = threadIdx.x >> 6;
    const int lane = threadIdx.x & 63;
    const int t    = threadIdx.x;
    const int qbase = qb * 128 + wave * 32;
    const int col   = lane & 31;
    const int g8    = (lane >> 5) * 8;

    const size_t qoff = ((size_t)h * LQ + qbase + col) * CH + g8;
    const bf16x8 ah0 = *(const bf16x8*)(qhi + qoff);
    const bf16x8 ah1 = *(const bf16x8*)(qhi + qoff + 16);

    int   rows[16];
    float thr[16];
    {
        const int rbase = h * LQ + qbase + 4 * (lane >> 5);
        #pragma unroll
        for (int r = 0; r < 16; ++r) {
            rows[r] = rbase + (r & 3) + 8 * (r >> 2);
            thr[r]  = ord_decode(maxhh_u[rows[r]]) - MARGIN;
        }
    }

    const unsigned short* kh = khi + ((size_t)h * SK + sc * 512) * CH;
    const int sbase = sc * 512;

    const int srow  = t >> 1;
    const int shalf = (t & 1) * 16;
    const unsigned short* sp = kh + (size_t)srow * CH + shalf;

    bf16x8 s0 = *(const bf16x8*)(sp);
    bf16x8 s1 = *(const bf16x8*)(sp + 8);
    *(bf16x8*)(&kbuf[0][srow * KROW + shalf])     = s0;
    *(bf16x8*)(&kbuf[0][srow * KROW + shalf + 8]) = s1;
    __syncthreads();

    for (int g = 0; g < 4; ++g) {
        if (g < 3) {
            const unsigned short* spn = sp + (size_t)(g + 1) * 128 * CH;
            s0 = *(const bf16x8*)(spn);
            s1 = *(const bf16x8*)(spn + 8);
        }
        const unsigned short* kbp = &kbuf[g & 1][0];
        #pragma unroll
        for (int tt = 0; tt < 4; ++tt) {
            const int rl = tt * 32 + col;
            const bf16x8 ka  = *(const bf16x8*)(kbp + rl * KROW + g8);
            const bf16x8 kbv = *(const bf16x8*)(kbp + rl * KROW + 16 + g8);
            f32x16 c = {0.f, 0.f, 0.f, 0.f, 0.f, 0.f, 0.f, 0.f,
                        0.f, 0.f, 0.f, 0.f, 0.f, 0.f, 0.f, 0.f};
            c = MFMA32(ah0, ka, c);
            c = MFMA32(ah1, kbv, c);

            unsigned int hit = 0u;
            #pragma unroll
            for (int r = 0; r < 16; ++r)
                hit = (c[r] >= thr[r]) ? (hit | (1u << r)) : hit;
            if (hit) {
                const int s = sbase + g * 128 + tt * 32 + col;
                #pragma unroll
                for (int r = 0; r < 16; ++r) {
                    if (hit & (1u << r)) {
                        const int slot = atomicAdd(&cnt[rows[r]], 1);
                        if (slot < CAP) cand[(size_t)rows[r] * CAP + slot] = s;
                    }
                }
            }
        }
        if (g < 3) {
            unsigned short* swn = &kbuf[(g + 1) & 1][srow * KROW + shalf];
            *(bf16x8*)(swn)     = s0;
            *(bf16x8*)(swn + 8) = s1;
            __syncthreads();
        }
    }
}

// ------------------------------------------------------------------
// Pass B: exact f32 refine (chain bit-identical to R2) + sigmoid +
// gather + scale; writes new_x0 as bf16 for the MFMA output GEMM.
// ------------------------------------------------------------------
__global__ __launch_bounds__(256)
void refine_gather_kernel(const float* __restrict__ qn,
                          const float* __restrict__ kn,
                          const int* __restrict__ cnt, const int* __restrict__ cand,
                          const float* __restrict__ xv,
                          const float* __restrict__ alpha, const float* __restrict__ beta,
                          unsigned short* __restrict__ nxb)  // (4,2048,256) bf16
{
    const int r = blockIdx.x * blockDim.x + threadIdx.x;  // h*2048 + l
    const int h = r >> 11, l = r & 2047;

    float qr[CH];
    #pragma unroll
    for (int i = 0; i < 8; ++i) {
        const float4 v = *(const float4*)(qn + (size_t)r * CH + i * 4);
        qr[i * 4 + 0] = v.x; qr[i * 4 + 1] = v.y;
        qr[i * 4 + 2] = v.z; qr[i * 4 + 3] = v.w;
    }

    int m = cnt[r];
    if (m > CAP) m = CAP;
    float best = -INFINITY;
    int   bidx = 0x7fffffff;
    for (int j = 0; j < m; ++j) {
        const int s = cand[(size_t)r * CAP + j];
        const float4* k4 = (const float4*)(kn + ((size_t)h * SK + s) * CH);
        float p = 0.f;
        #pragma unroll
        for (int c = 0; c < 8; ++c) {
            const float4 kv = k4[c];
            p = fmaf(qr[c * 4 + 0], kv.x, p);
            p = fmaf(qr[c * 4 + 1], kv.y, p);
            p = fmaf(qr[c * 4 + 2], kv.z, p);
            p = fmaf(qr[c * 4 + 3], kv.w, p);
        }
        if (p > best || (p == best && s < bidx)) { best = p; bidx = s; }
    }
    if (bidx == 0x7fffffff) bidx = 0;   // unreachable guard

    const float a = alpha[0], be = beta[0];
    float tv;
    int idx = bidx;
    if (a == 0.f) { idx = 0; tv = be; }
    else          { tv = fmaf(fabsf(a), best, be); }
    float val;
    if (tv >= 0.f) val = 1.f / (1.f + expf(-tv));
    else           { const float e = expf(tv); val = e / (1.f + e); }

    const float4* vr = (const float4*)(xv + ((size_t)h * SK + idx) * CH);
    const int n = h >> 3, f = h & 7;
    unsigned short* out = nxb + (((size_t)n * LQ + l) * (FC * CH)) + f * CH;
    #pragma unroll
    for (int i = 0; i < 8; ++i) {
        const float4 w = vr[i];
        ushort8v o;
        o[0] = f32_to_bf16_bits(w.x * val);
        o[1] = f32_to_bf16_bits(w.y * val);
        o[2] = f32_to_bf16_bits(w.z * val);
        o[3] = f32_to_bf16_bits(w.w * val);
        *(unsigned long long*)(out + i * 4) = __builtin_bit_cast(unsigned long long,
            *(const ulong1*)&o);
    }
}

// ------------------------------------------------------------------
// K6: out = nx(bf16) @ Wm(bf16 swizzled) + bm, f32 out. MFMA 32x32.
// ------------------------------------------------------------------
__global__ __launch_bounds__(256)
void gemm_out_mfma_kernel(const unsigned short* __restrict__ nxb,
                          const unsigned short* __restrict__ wm_s,
                          const float* __restrict__ bm, float* __restrict__ out)
{
    const int wave = threadIdx.x >> 6;
    const int lane = threadIdx.x & 63;
    const int idx  = blockIdx.x * 4 + wave;
    const int mt   = idx >> 3;
    const int nt   = idx & 7;
    const int col  = lane & 31;
    const int g8   = (lane >> 5) * 8;

    const unsigned short* aptr = nxb + (size_t)(mt * 32 + col) * 256 + g8;
    const unsigned short* bptr = wm_s + nt * 32 * 16 + col * 16 + g8;

    f32x16 acc = {0.f, 0.f, 0.f, 0.f, 0.f, 0.f, 0.f, 0.f,
                  0.f, 0.f, 0.f, 0.f, 0.f, 0.f, 0.f, 0.f};
    #pragma unroll 4
    for (int kc = 0; kc < 16; ++kc) {
        const bf16x8 a = *(const bf16x8*)(aptr + kc * 16);
        const bf16x8 bfr = *(const bf16x8*)(bptr + (size_t)kc * 4096);
        acc = MFMA32(a, bfr, acc);
    }

    const int n0 = nt * 32;
    const float bias = bm[n0 + col];
    #pragma unroll
    for (int r = 0; r < 16; ++r) {
        const int row = mt * 32 + (r & 3) + 8 * (r >> 2) + 4 * (lane >> 5);
        out[(size_t)row * 256 + n0 + col] = acc[r] + bias;
    }
}

// ------------------------------------------------------------------
extern "C" void kernel_launch(void* const* d_in, const int* in_sizes, int n_in,
                              void* d_out, int out_size, void* d_ws, size_t ws_size,
                              hipStream_t stream)
{
    const float* x0 = (const float*)d_in[0];
    const float* x1 = (const float*)d_in[1];
    const float* W0 = (const float*)d_in[2];
    const float* b0 = (const float*)d_in[3];
    const float* W1 = (const float*)d_in[4];
    const float* b1 = (const float*)d_in[5];
    const float* Wm = (const float*)d_in[6];
    const float* bm = (const float*)d_in[7];
    const float* alpha = (const float*)d_in[8];
    const float* beta  = (const float*)d_in[9];
    float* out = (float*)d_out;

    char* ws = (char*)d_ws;
    const size_t MB = 1024ull * 1024ull;
    float* x0q = (float*)(ws + 0);          // (32,2048,32) f32 normalized
    float* x1k = (float*)(ws + 8 * MB);     // (32,2048,32) f32 normalized
    float* x1v = (float*)(ws + 16 * MB);    // (32,2048,32) f32 values
    unsigned short* qhi = (unsigned short*)(ws + 24 * MB);  // 4MB (dead after scan)
    unsigned short* khi = (unsigned short*)(ws + 28 * MB);  // 4MB
    unsigned short* x1b = (unsigned short*)(ws + 32 * MB);  // 4MB (dead after valgemm)
    int* cand = (int*)(ws + 32 * MB);       // 4MB CAP16 (reuses x1b; valgemm reads
                                            // x1b before candpass writes cand)
    unsigned int* maxhh_u = (unsigned int*)(ws + 36 * MB);          // 256KB
    int* cnt  = (int*)(ws + 36 * MB + 256 * 1024);                  // 256KB
    unsigned short* wm_s = (unsigned short*)(ws + 36 * MB + 512 * 1024); // 128KB
    unsigned short* wv_s = (unsigned short*)(ws + 36 * MB + 640 * 1024); // 128KB
    unsigned short* nxb  = (unsigned short*)(ws + 24 * MB); // reuse qhi region

    const int Mrows = NB * LQ;   // 8192

    // 1) exact-f32 projections + fused norm/bf16-split (argmax path)
    proj_gemm_kernel<<<dim3(8, Mrows / 64), 256, 0, stream>>>(
        x0, x1, W0, b0, W1, b1, alpha, x0q, x1k, qhi, khi);
    // 2) preps: x1->bf16, Wm & W1-value swizzles, zero maxhh/cnt
    prep_kernel<<<2048, 256, 0, stream>>>(x1, Wm, W1, x1b, wm_s, wv_s, maxhh_u, cnt);
    // 3) value projection via bf16 MFMA
    val_gemm_kernel<<<512, 256, 0, stream>>>(x1b, wv_s, b1, x1v);
    // 4) global hh max (R13-proven 4-wave LDS-staged, x4 split)
    maxpass_kernel<<<2048, 256, 0, stream>>>(qhi, khi, maxhh_u);
    // 5) candidate collection vs global threshold (R13-proven)
    candpass_kernel<<<2048, 256, 0, stream>>>(qhi, khi, maxhh_u, cnt, cand);
    // 6) exact refine + sigmoid + gather + scale -> bf16 nx
    refine_gather_kernel<<<(MHEAD * LQ) / 256, 256, 0, stream>>>(
        x0q, x1k, cnt, cand, x1v, alpha, beta, nxb);
    // 7) out = nx @ Wm + bm via bf16 MFMA
    gemm_out_mfma_kernel<<<512, 256, 0, stream>>>(nxb, wm_s, bm, out);
}